// Round 4
// baseline (423.658 us; speedup 1.0000x reference)
//
#include <hip/hip_runtime.h>

#define NROWS 65536
#define DDIM  512
#define NCLS  64

typedef __attribute__((ext_vector_type(4))) float  floatx4;
typedef __attribute__((ext_vector_type(8))) short  shortx8;

static constexpr float SCALE = 0.25f / (float)NROWS;  // (1-GLW)/2 = GLW/2 = 0.25, / N

// ws byte offsets
static constexpr size_t OFF_SUMS   = 0;        // f32 [64][512] = 131072 B (plain stores)
static constexpr size_t OFF_HIST   = 131072;   // int [64]
static constexpr size_t OFF_CURSOR = 131328;   // int [64]
static constexpr size_t OFF_IDX    = 131584;   // int [65536] = 262144 B

__device__ __forceinline__ unsigned short f2bf(float f) {  // round-to-nearest-even
  unsigned u = __float_as_uint(f);
  return (unsigned short)((u + 0x7fffu + ((u >> 16) & 1u)) >> 16);
}

// 64 blocks x 256 threads x 4 rows (int4)
__global__ __launch_bounds__(256) void k_hist(const int* __restrict__ seg,
                                              int* __restrict__ hist) {
  __shared__ int h[NCLS];
  const int t = threadIdx.x;
  if (t < NCLS) h[t] = 0;
  __syncthreads();
  const int4 v = ((const int4*)seg)[blockIdx.x * 256 + t];
  atomicAdd(&h[v.x], 1); atomicAdd(&h[v.y], 1);
  atomicAdd(&h[v.z], 1); atomicAdd(&h[v.w], 1);
  __syncthreads();
  if (t < NCLS) atomicAdd(&hist[t], h[t]);
}

// 32 blocks x 1024 threads x 2 rows. Rank via LDS atomic, base via one global
// atomic per class per block; global starts from hist via wave shfl-scan.
__global__ __launch_bounds__(1024) void k_scatter2(const int* __restrict__ seg,
                                                   const int* __restrict__ hist,
                                                   int* __restrict__ cursor,
                                                   int* __restrict__ idx) {
  __shared__ int lhist[NCLS];
  __shared__ int gbase[NCLS];
  const int t = threadIdx.x;
  if (t < NCLS) lhist[t] = 0;
  __syncthreads();
  const int i0 = blockIdx.x * 2048 + t;
  const int lab0 = seg[i0];
  const int r0 = atomicAdd(&lhist[lab0], 1);
  const int i1 = i0 + 1024;
  const int lab1 = seg[i1];
  const int r1 = atomicAdd(&lhist[lab1], 1);
  __syncthreads();
  if (t < NCLS) {
    const int h = hist[t];
    int x = h;
#pragma unroll
    for (int off = 1; off < 64; off <<= 1) {
      const int y = __shfl_up(x, off, 64);
      if (t >= off) x += y;
    }
    gbase[t] = (x - h) + atomicAdd(&cursor[t], lhist[t]);
  }
  __syncthreads();
  idx[gbase[lab0] + r0] = i0;
  idx[gbase[lab1] + r1] = i1;
}

// 512 blocks = 64 classes x 8 col-eighths. Register accumulation over the
// class's contiguous row list with idx software-prefetch; LDS reduce; store.
__global__ __launch_bounds__(256) void k_sumsC(const float* __restrict__ S1,
                                               const int* __restrict__ idx,
                                               const int* __restrict__ hist,
                                               float* __restrict__ sums) {
  __shared__ int sh_start[NCLS + 1];
  __shared__ float red[256];
  const int c  = blockIdx.x >> 3;
  const int qq = blockIdx.x & 7;
  const int t  = threadIdx.x;
  if (t < 64) {
    const int h = hist[t];
    int x = h;
#pragma unroll
    for (int off = 1; off < 64; off <<= 1) {
      const int y = __shfl_up(x, off, 64);
      if (t >= off) x += y;
    }
    sh_start[t] = x - h;
    if (t == 63) sh_start[64] = x;
  }
  __syncthreads();
  const int s0 = sh_start[c];
  const int n  = sh_start[c + 1] - s0;
  const int sub = t >> 6;
  const int col = qq * 64 + (t & 63);
  const int n4 = n >> 2;
  const int base = s0 + sub * n4;
  const int len  = (sub == 3) ? (n - 3 * n4) : n4;
  const float* Sc = S1 + col;
  const int* ip = idx + base;
  float a0 = 0.f, a1 = 0.f, a2 = 0.f, a3 = 0.f;
  int j = 0;
  if (len >= 8) {
    int r[8];
#pragma unroll
    for (int q = 0; q < 8; ++q) r[q] = ip[q];
    for (; j + 16 <= len; j += 8) {
      int nr[8];
#pragma unroll
      for (int q = 0; q < 8; ++q) nr[q] = ip[j + 8 + q];
      a0 += Sc[(size_t)r[0] * DDIM]; a1 += Sc[(size_t)r[1] * DDIM];
      a2 += Sc[(size_t)r[2] * DDIM]; a3 += Sc[(size_t)r[3] * DDIM];
      a0 += Sc[(size_t)r[4] * DDIM]; a1 += Sc[(size_t)r[5] * DDIM];
      a2 += Sc[(size_t)r[6] * DDIM]; a3 += Sc[(size_t)r[7] * DDIM];
#pragma unroll
      for (int q = 0; q < 8; ++q) r[q] = nr[q];
    }
    a0 += Sc[(size_t)r[0] * DDIM]; a1 += Sc[(size_t)r[1] * DDIM];
    a2 += Sc[(size_t)r[2] * DDIM]; a3 += Sc[(size_t)r[3] * DDIM];
    a0 += Sc[(size_t)r[4] * DDIM]; a1 += Sc[(size_t)r[5] * DDIM];
    a2 += Sc[(size_t)r[6] * DDIM]; a3 += Sc[(size_t)r[7] * DDIM];
    j += 8;
  }
  for (; j < len; ++j) a0 += Sc[(size_t)idx[base + j] * DDIM];
  red[t] = a0 + a1 + a2 + a3;
  __syncthreads();
  if (t < 64)
    sums[(size_t)c * DDIM + col] = red[t] + red[t + 64] + red[t + 128] + red[t + 192];
}

// Persistent barrier-free GEMM+CE. 512 blocks x 512 threads, 256 rows/block.
// Cent staged to LDS once (fused divide+bf16, XOR-swizzled 16B granules).
// Each wave: 16 rows x 64 classes, A-frags direct from global w/ 1-chunk prefetch.
__global__ __launch_bounds__(512, 4) void k_loss(const float* __restrict__ S1,
                                                 const float* __restrict__ S2,
                                                 const int* __restrict__ seg,
                                                 const float* __restrict__ sim,
                                                 const float* __restrict__ sums,
                                                 const int* __restrict__ hist,
                                                 float* __restrict__ out) {
  __shared__ short cent[NCLS * DDIM];  // 64 KB, [class][k] swizzled: g' = g ^ (class&7)
  __shared__ float red8[8];
  const int t = threadIdx.x;

  {  // stage centroids: fused sums/count * 1/TEMP -> bf16
    const int cls = t >> 3;
    const float inv = 10.0f / (float)hist[cls];
    const float* sp = sums + (size_t)cls * DDIM;
#pragma unroll
    for (int i = 0; i < 8; ++i) {
      const int g = (t & 7) + i * 8;              // 16B granule index 0..63
      const float4 x = *(const float4*)(sp + g * 8);
      const float4 y = *(const float4*)(sp + g * 8 + 4);
      shortx8 b;
      b[0] = (short)f2bf(x.x * inv); b[1] = (short)f2bf(x.y * inv);
      b[2] = (short)f2bf(x.z * inv); b[3] = (short)f2bf(x.w * inv);
      b[4] = (short)f2bf(y.x * inv); b[5] = (short)f2bf(y.y * inv);
      b[6] = (short)f2bf(y.z * inv); b[7] = (short)f2bf(y.w * inv);
      *(shortx8*)&cent[cls * DDIM + ((g ^ (cls & 7)) * 8)] = b;
    }
  }
  __syncthreads();

  const int w    = t >> 6;
  const int lane = t & 63;
  const int n    = lane & 15;
  const int quad = lane >> 4;
  const int vb   = blockIdx.x * 256;
  const bool isS2 = (vb >= NROWS);
  const float* S = isS2 ? S2 : S1;
  const int i0m = isS2 ? (vb - NROWS) : vb;

  float loss_acc = 0.f;
#pragma unroll 1
  for (int s = 0; s < 2; ++s) {
    const int row0 = i0m + s * 128 + w * 16;
    const float* Srow = S + (size_t)(row0 + n) * DDIM;  // lane's A-row
    floatx4 acc0 = {0,0,0,0}, acc1 = {0,0,0,0}, acc2 = {0,0,0,0}, acc3 = {0,0,0,0};
    float4 aLo = *(const float4*)(Srow + quad * 8);
    float4 aHi = *(const float4*)(Srow + quad * 8 + 4);
#pragma unroll
    for (int c = 0; c < 16; ++c) {
      float4 nLo, nHi;
      if (c < 15) {
        nLo = *(const float4*)(Srow + (c + 1) * 32 + quad * 8);
        nHi = *(const float4*)(Srow + (c + 1) * 32 + quad * 8 + 4);
      }
      shortx8 af;
      af[0] = (short)f2bf(aLo.x); af[1] = (short)f2bf(aLo.y);
      af[2] = (short)f2bf(aLo.z); af[3] = (short)f2bf(aLo.w);
      af[4] = (short)f2bf(aHi.x); af[5] = (short)f2bf(aHi.y);
      af[6] = (short)f2bf(aHi.z); af[7] = (short)f2bf(aHi.w);
      const int gp = ((c * 4 + quad) ^ (n & 7)) * 8;
      const shortx8 b0 = *(const shortx8*)&cent[(0  + n) * DDIM + gp];
      acc0 = __builtin_amdgcn_mfma_f32_16x16x32_bf16(af, b0, acc0, 0, 0, 0);
      const shortx8 b1 = *(const shortx8*)&cent[(16 + n) * DDIM + gp];
      acc1 = __builtin_amdgcn_mfma_f32_16x16x32_bf16(af, b1, acc1, 0, 0, 0);
      const shortx8 b2 = *(const shortx8*)&cent[(32 + n) * DDIM + gp];
      acc2 = __builtin_amdgcn_mfma_f32_16x16x32_bf16(af, b2, acc2, 0, 0, 0);
      const shortx8 b3 = *(const shortx8*)&cent[(48 + n) * DDIM + gp];
      acc3 = __builtin_amdgcn_mfma_f32_16x16x32_bf16(af, b3, acc3, 0, 0, 0);
      aLo = nLo; aHi = nHi;
    }
    // in-register CE epilogue. Row R = quad*4 + r; lane holds classes {n,16+n,32+n,48+n}.
    float ce4[4];
#pragma unroll
    for (int r = 0; r < 4; ++r) {
      float mx = fmaxf(fmaxf(acc0[r], acc1[r]), fmaxf(acc2[r], acc3[r]));
      mx = fmaxf(mx, __shfl_xor(mx, 1, 16));
      mx = fmaxf(mx, __shfl_xor(mx, 2, 16));
      mx = fmaxf(mx, __shfl_xor(mx, 4, 16));
      mx = fmaxf(mx, __shfl_xor(mx, 8, 16));
      float se = __expf(acc0[r] - mx) + __expf(acc1[r] - mx) +
                 __expf(acc2[r] - mx) + __expf(acc3[r] - mx);
      se += __shfl_xor(se, 1, 16);
      se += __shfl_xor(se, 2, 16);
      se += __shfl_xor(se, 4, 16);
      se += __shfl_xor(se, 8, 16);
      const int lab = seg[row0 + quad * 4 + r];   // quad-uniform
      const int ctl = lab >> 4, nl = lab & 15;
      float v = (ctl == 0) ? acc0[r] : (ctl == 1) ? acc1[r]
              : (ctl == 2) ? acc2[r] : acc3[r];
      const float lv = __shfl(v, nl, 16);         // lane quad*16+nl
      ce4[r] = mx + __logf(se) - lv;
    }
    if (n < 4) {  // lane n handles row quad*4 + n
      const int R = row0 + quad * 4 + n;
      const float4* sp4 = (const float4*)&sim[(size_t)R * 16];
      const float4 w0 = sp4[0], w1 = sp4[1], w2 = sp4[2], w3 = sp4[3];
      const float wgt = (w0.x + w0.y + w0.z + w0.w + w1.x + w1.y + w1.z + w1.w +
                         w2.x + w2.y + w2.z + w2.w + w3.x + w3.y + w3.z + w3.w) * (1.0f / 16.0f);
      loss_acc += ce4[n] * wgt;
    }
  }

  float v = loss_acc * SCALE;
#pragma unroll
  for (int off = 1; off < 64; off <<= 1) v += __shfl_xor(v, off, 64);
  if (lane == 0) red8[w] = v;
  __syncthreads();
  if (t == 0) {
    float sacc = red8[0] + red8[1] + red8[2] + red8[3] +
                 red8[4] + red8[5] + red8[6] + red8[7];
    atomicAdd(out, sacc);
  }
}

extern "C" void kernel_launch(void* const* d_in, const int* in_sizes, int n_in,
                              void* d_out, int out_size, void* d_ws, size_t ws_size,
                              hipStream_t stream) {
  const float* S1  = (const float*)d_in[0];
  const float* S2  = (const float*)d_in[1];
  const int*   seg = (const int*)d_in[2];
  const float* sim = (const float*)d_in[3];
  char* ws = (char*)d_ws;
  float* sums   = (float*)(ws + OFF_SUMS);
  int*   hist   = (int*)(ws + OFF_HIST);
  int*   cursor = (int*)(ws + OFF_CURSOR);
  int*   idx    = (int*)(ws + OFF_IDX);
  float* out = (float*)d_out;

  hipMemsetAsync(ws + OFF_HIST, 0, 512, stream);   // hist + cursor
  hipMemsetAsync(d_out, 0, sizeof(float), stream);

  k_hist<<<64, 256, 0, stream>>>(seg, hist);
  k_scatter2<<<32, 1024, 0, stream>>>(seg, hist, cursor, idx);
  k_sumsC<<<512, 256, 0, stream>>>(S1, idx, hist, sums);
  k_loss<<<512, 512, 0, stream>>>(S1, S2, seg, sim, sums, hist, out);
}

// Round 5
// 310.688 us; speedup vs baseline: 1.3636x; 1.3636x over previous
//
#include <hip/hip_runtime.h>

#define NROWS 65536
#define DDIM  512
#define NCLS  64

typedef __attribute__((ext_vector_type(4))) float  floatx4;
typedef __attribute__((ext_vector_type(8))) short  shortx8;

static constexpr float SCALE = 0.25f / (float)NROWS;  // (1-GLW)/2 = GLW/2 = 0.25, / N

// ws byte offsets
static constexpr size_t OFF_SUMS   = 0;        // f32 [64][512] = 131072 B (plain stores)
static constexpr size_t OFF_HIST   = 131072;   // int [64]
static constexpr size_t OFF_CURSOR = 131328;   // int [64]
static constexpr size_t OFF_IDX    = 131584;   // int [65536] = 262144 B

__device__ __forceinline__ unsigned short f2bf(float f) {  // round-to-nearest-even
  unsigned u = __float_as_uint(f);
  return (unsigned short)((u + 0x7fffu + ((u >> 16) & 1u)) >> 16);
}

// 64 blocks x 256 threads x 4 rows (int4)
__global__ __launch_bounds__(256) void k_hist(const int* __restrict__ seg,
                                              int* __restrict__ hist) {
  __shared__ int h[NCLS];
  const int t = threadIdx.x;
  if (t < NCLS) h[t] = 0;
  __syncthreads();
  const int4 v = ((const int4*)seg)[blockIdx.x * 256 + t];
  atomicAdd(&h[v.x], 1); atomicAdd(&h[v.y], 1);
  atomicAdd(&h[v.z], 1); atomicAdd(&h[v.w], 1);
  __syncthreads();
  if (t < NCLS) atomicAdd(&hist[t], h[t]);
}

// 32 blocks x 1024 threads x 2 rows. Rank via LDS atomic, base via one global
// atomic per class per block; global starts from hist via wave shfl-scan.
__global__ __launch_bounds__(1024) void k_scatter2(const int* __restrict__ seg,
                                                   const int* __restrict__ hist,
                                                   int* __restrict__ cursor,
                                                   int* __restrict__ idx) {
  __shared__ int lhist[NCLS];
  __shared__ int gbase[NCLS];
  const int t = threadIdx.x;
  if (t < NCLS) lhist[t] = 0;
  __syncthreads();
  const int i0 = blockIdx.x * 2048 + t;
  const int lab0 = seg[i0];
  const int r0 = atomicAdd(&lhist[lab0], 1);
  const int i1 = i0 + 1024;
  const int lab1 = seg[i1];
  const int r1 = atomicAdd(&lhist[lab1], 1);
  __syncthreads();
  if (t < NCLS) {
    const int h = hist[t];
    int x = h;
#pragma unroll
    for (int off = 1; off < 64; off <<= 1) {
      const int y = __shfl_up(x, off, 64);
      if (t >= off) x += y;
    }
    gbase[t] = (x - h) + atomicAdd(&cursor[t], lhist[t]);
  }
  __syncthreads();
  idx[gbase[lab0] + r0] = i0;
  idx[gbase[lab1] + r1] = i1;
}

// 512 blocks = 64 classes x 8 col-eighths. Register accumulation over the
// class's contiguous row list with idx software-prefetch; LDS reduce; store.
__global__ __launch_bounds__(256) void k_sumsC(const float* __restrict__ S1,
                                               const int* __restrict__ idx,
                                               const int* __restrict__ hist,
                                               float* __restrict__ sums) {
  __shared__ int sh_start[NCLS + 1];
  __shared__ float red[256];
  const int c  = blockIdx.x >> 3;
  const int qq = blockIdx.x & 7;
  const int t  = threadIdx.x;
  if (t < 64) {
    const int h = hist[t];
    int x = h;
#pragma unroll
    for (int off = 1; off < 64; off <<= 1) {
      const int y = __shfl_up(x, off, 64);
      if (t >= off) x += y;
    }
    sh_start[t] = x - h;
    if (t == 63) sh_start[64] = x;
  }
  __syncthreads();
  const int s0 = sh_start[c];
  const int n  = sh_start[c + 1] - s0;
  const int sub = t >> 6;
  const int col = qq * 64 + (t & 63);
  const int n4 = n >> 2;
  const int base = s0 + sub * n4;
  const int len  = (sub == 3) ? (n - 3 * n4) : n4;
  const float* Sc = S1 + col;
  const int* ip = idx + base;
  float a0 = 0.f, a1 = 0.f, a2 = 0.f, a3 = 0.f;
  int j = 0;
  if (len >= 8) {
    int r[8];
#pragma unroll
    for (int q = 0; q < 8; ++q) r[q] = ip[q];
    for (; j + 16 <= len; j += 8) {
      int nr[8];
#pragma unroll
      for (int q = 0; q < 8; ++q) nr[q] = ip[j + 8 + q];
      a0 += Sc[(size_t)r[0] * DDIM]; a1 += Sc[(size_t)r[1] * DDIM];
      a2 += Sc[(size_t)r[2] * DDIM]; a3 += Sc[(size_t)r[3] * DDIM];
      a0 += Sc[(size_t)r[4] * DDIM]; a1 += Sc[(size_t)r[5] * DDIM];
      a2 += Sc[(size_t)r[6] * DDIM]; a3 += Sc[(size_t)r[7] * DDIM];
#pragma unroll
      for (int q = 0; q < 8; ++q) r[q] = nr[q];
    }
    a0 += Sc[(size_t)r[0] * DDIM]; a1 += Sc[(size_t)r[1] * DDIM];
    a2 += Sc[(size_t)r[2] * DDIM]; a3 += Sc[(size_t)r[3] * DDIM];
    a0 += Sc[(size_t)r[4] * DDIM]; a1 += Sc[(size_t)r[5] * DDIM];
    a2 += Sc[(size_t)r[6] * DDIM]; a3 += Sc[(size_t)r[7] * DDIM];
    j += 8;
  }
  for (; j < len; ++j) a0 += Sc[(size_t)idx[base + j] * DDIM];
  red[t] = a0 + a1 + a2 + a3;
  __syncthreads();
  if (t < 64)
    sums[(size_t)c * DDIM + col] = red[t] + red[t + 64] + red[t + 128] + red[t + 192];
}

// Persistent barrier-free GEMM+CE. 512 blocks x 512 threads, 256 rows/block.
// Cent staged to LDS once (fused divide+bf16, XOR-swizzled 16B granules).
// K-loop: unroll 1 + branchless depth-1 prefetch (no spill); epilogue has no
// dynamically-indexed locals (no scratch).
__global__ __launch_bounds__(512, 4) void k_loss(const float* __restrict__ S1,
                                                 const float* __restrict__ S2,
                                                 const int* __restrict__ seg,
                                                 const float* __restrict__ sim,
                                                 const float* __restrict__ sums,
                                                 const int* __restrict__ hist,
                                                 float* __restrict__ out) {
  __shared__ short cent[NCLS * DDIM];  // 64 KB, [class][k] swizzled: g' = g ^ (class&7)
  __shared__ float red8[8];
  const int t = threadIdx.x;

  {  // stage centroids: fused sums/count * 1/TEMP -> bf16
    const int cls = t >> 3;
    const float inv = 10.0f / (float)hist[cls];
    const float* sp = sums + (size_t)cls * DDIM;
#pragma unroll
    for (int i = 0; i < 8; ++i) {
      const int g = (t & 7) + i * 8;              // 16B granule index 0..63
      const float4 x = *(const float4*)(sp + g * 8);
      const float4 y = *(const float4*)(sp + g * 8 + 4);
      shortx8 b;
      b[0] = (short)f2bf(x.x * inv); b[1] = (short)f2bf(x.y * inv);
      b[2] = (short)f2bf(x.z * inv); b[3] = (short)f2bf(x.w * inv);
      b[4] = (short)f2bf(y.x * inv); b[5] = (short)f2bf(y.y * inv);
      b[6] = (short)f2bf(y.z * inv); b[7] = (short)f2bf(y.w * inv);
      *(shortx8*)&cent[cls * DDIM + ((g ^ (cls & 7)) * 8)] = b;
    }
  }
  __syncthreads();

  const int w    = t >> 6;
  const int lane = t & 63;
  const int n    = lane & 15;
  const int quad = lane >> 4;
  const int vb   = blockIdx.x * 256;
  const bool isS2 = (vb >= NROWS);
  const float* S = isS2 ? S2 : S1;
  const int i0m = isS2 ? (vb - NROWS) : vb;

  float loss_acc = 0.f;
#pragma unroll 1
  for (int s = 0; s < 2; ++s) {
    const int row0 = i0m + s * 128 + w * 16;
    const float* Srow = S + (size_t)(row0 + n) * DDIM;  // lane's A-row
    floatx4 acc0 = {0,0,0,0}, acc1 = {0,0,0,0}, acc2 = {0,0,0,0}, acc3 = {0,0,0,0};
    float4 aLo = *(const float4*)(Srow + quad * 8);
    float4 aHi = *(const float4*)(Srow + quad * 8 + 4);
#pragma unroll 1
    for (int c = 0; c < 16; ++c) {
      const int cn = (c + 1) & 15;   // branchless wrap (c=15 reloads warm line)
      const float4 nLo = *(const float4*)(Srow + cn * 32 + quad * 8);
      const float4 nHi = *(const float4*)(Srow + cn * 32 + quad * 8 + 4);
      shortx8 af;
      af[0] = (short)f2bf(aLo.x); af[1] = (short)f2bf(aLo.y);
      af[2] = (short)f2bf(aLo.z); af[3] = (short)f2bf(aLo.w);
      af[4] = (short)f2bf(aHi.x); af[5] = (short)f2bf(aHi.y);
      af[6] = (short)f2bf(aHi.z); af[7] = (short)f2bf(aHi.w);
      const int gp = ((c * 4 + quad) ^ (n & 7)) * 8;
      const shortx8 b0 = *(const shortx8*)&cent[(0  + n) * DDIM + gp];
      acc0 = __builtin_amdgcn_mfma_f32_16x16x32_bf16(af, b0, acc0, 0, 0, 0);
      const shortx8 b1 = *(const shortx8*)&cent[(16 + n) * DDIM + gp];
      acc1 = __builtin_amdgcn_mfma_f32_16x16x32_bf16(af, b1, acc1, 0, 0, 0);
      const shortx8 b2 = *(const shortx8*)&cent[(32 + n) * DDIM + gp];
      acc2 = __builtin_amdgcn_mfma_f32_16x16x32_bf16(af, b2, acc2, 0, 0, 0);
      const shortx8 b3 = *(const shortx8*)&cent[(48 + n) * DDIM + gp];
      acc3 = __builtin_amdgcn_mfma_f32_16x16x32_bf16(af, b3, acc3, 0, 0, 0);
      aLo = nLo; aHi = nHi;
    }
    // in-register CE epilogue. Row R = quad*4 + r; lane holds classes {n,16+n,32+n,48+n}.
#pragma unroll
    for (int r = 0; r < 4; ++r) {
      float mx = fmaxf(fmaxf(acc0[r], acc1[r]), fmaxf(acc2[r], acc3[r]));
      mx = fmaxf(mx, __shfl_xor(mx, 1, 16));
      mx = fmaxf(mx, __shfl_xor(mx, 2, 16));
      mx = fmaxf(mx, __shfl_xor(mx, 4, 16));
      mx = fmaxf(mx, __shfl_xor(mx, 8, 16));
      float se = __expf(acc0[r] - mx) + __expf(acc1[r] - mx) +
                 __expf(acc2[r] - mx) + __expf(acc3[r] - mx);
      se += __shfl_xor(se, 1, 16);
      se += __shfl_xor(se, 2, 16);
      se += __shfl_xor(se, 4, 16);
      se += __shfl_xor(se, 8, 16);
      const int lab = seg[row0 + quad * 4 + r];   // group-uniform
      const int ctl = lab >> 4, nl = lab & 15;
      float v = (ctl == 0) ? acc0[r] : (ctl == 1) ? acc1[r]
              : (ctl == 2) ? acc2[r] : acc3[r];
      const float lv = __shfl(v, nl, 16);         // class-lab logit
      const float ce = mx + __logf(se) - lv;
      if (n == r) {                               // lane r of each 16-group owns row quad*4+r
        const int R = row0 + quad * 4 + r;
        const float4* sp4 = (const float4*)&sim[(size_t)R * 16];
        const float4 w0 = sp4[0], w1 = sp4[1], w2 = sp4[2], w3 = sp4[3];
        const float wgt = (w0.x + w0.y + w0.z + w0.w + w1.x + w1.y + w1.z + w1.w +
                           w2.x + w2.y + w2.z + w2.w + w3.x + w3.y + w3.z + w3.w) * (1.0f / 16.0f);
        loss_acc += ce * wgt;
      }
    }
  }

  float v = loss_acc * SCALE;
#pragma unroll
  for (int off = 1; off < 64; off <<= 1) v += __shfl_xor(v, off, 64);
  if (lane == 0) red8[w] = v;
  __syncthreads();
  if (t == 0) {
    float sacc = red8[0] + red8[1] + red8[2] + red8[3] +
                 red8[4] + red8[5] + red8[6] + red8[7];
    atomicAdd(out, sacc);
  }
}

extern "C" void kernel_launch(void* const* d_in, const int* in_sizes, int n_in,
                              void* d_out, int out_size, void* d_ws, size_t ws_size,
                              hipStream_t stream) {
  const float* S1  = (const float*)d_in[0];
  const float* S2  = (const float*)d_in[1];
  const int*   seg = (const int*)d_in[2];
  const float* sim = (const float*)d_in[3];
  char* ws = (char*)d_ws;
  float* sums   = (float*)(ws + OFF_SUMS);
  int*   hist   = (int*)(ws + OFF_HIST);
  int*   cursor = (int*)(ws + OFF_CURSOR);
  int*   idx    = (int*)(ws + OFF_IDX);
  float* out = (float*)d_out;

  hipMemsetAsync(ws + OFF_HIST, 0, 512, stream);   // hist + cursor
  hipMemsetAsync(d_out, 0, sizeof(float), stream);

  k_hist<<<64, 256, 0, stream>>>(seg, hist);
  k_scatter2<<<32, 1024, 0, stream>>>(seg, hist, cursor, idx);
  k_sumsC<<<512, 256, 0, stream>>>(S1, idx, hist, sums);
  k_loss<<<512, 512, 0, stream>>>(S1, S2, seg, sim, sums, hist, out);
}

// Round 6
// 309.307 us; speedup vs baseline: 1.3697x; 1.0045x over previous
//
#include <hip/hip_runtime.h>

#define NROWS 65536
#define DDIM  512
#define NCLS  64

typedef __attribute__((ext_vector_type(4))) float  floatx4;
typedef __attribute__((ext_vector_type(8))) short  shortx8;

static constexpr float SCALE = 0.25f / (float)NROWS;  // (1-GLW)/2 = GLW/2 = 0.25, / N

// ws byte offsets
static constexpr size_t OFF_SUMS   = 0;        // f32 [64][512] = 131072 B (zeroed by k_scatter2)
static constexpr size_t OFF_HIST   = 131072;   // int [64]
static constexpr size_t OFF_CURSOR = 131328;   // int [64]
static constexpr size_t OFF_IDX    = 131584;   // int [65536] = 262144 B

__device__ __forceinline__ unsigned short f2bf(float f) {  // round-to-nearest-even
  unsigned u = __float_as_uint(f);
  return (unsigned short)((u + 0x7fffu + ((u >> 16) & 1u)) >> 16);
}

// 64 blocks x 256 threads x 4 rows (int4)
__global__ __launch_bounds__(256) void k_hist(const int* __restrict__ seg,
                                              int* __restrict__ hist) {
  __shared__ int h[NCLS];
  const int t = threadIdx.x;
  if (t < NCLS) h[t] = 0;
  __syncthreads();
  const int4 v = ((const int4*)seg)[blockIdx.x * 256 + t];
  atomicAdd(&h[v.x], 1); atomicAdd(&h[v.y], 1);
  atomicAdd(&h[v.z], 1); atomicAdd(&h[v.w], 1);
  __syncthreads();
  if (t < NCLS) atomicAdd(&hist[t], h[t]);
}

// 32 blocks x 1024 threads x 2 rows. Rank via LDS atomic, base via one global
// atomic per class per block; global starts from hist via wave shfl-scan.
// Also zeroes sums[32768] (one float per thread) for k_sumsC's atomics.
__global__ __launch_bounds__(1024) void k_scatter2(const int* __restrict__ seg,
                                                   const int* __restrict__ hist,
                                                   int* __restrict__ cursor,
                                                   int* __restrict__ idx,
                                                   float* __restrict__ sums) {
  __shared__ int lhist[NCLS];
  __shared__ int gbase[NCLS];
  const int t = threadIdx.x;
  sums[blockIdx.x * 1024 + t] = 0.f;   // 32*1024 == 64*512 exactly
  if (t < NCLS) lhist[t] = 0;
  __syncthreads();
  const int i0 = blockIdx.x * 2048 + t;
  const int lab0 = seg[i0];
  const int r0 = atomicAdd(&lhist[lab0], 1);
  const int i1 = i0 + 1024;
  const int lab1 = seg[i1];
  const int r1 = atomicAdd(&lhist[lab1], 1);
  __syncthreads();
  if (t < NCLS) {
    const int h = hist[t];
    int x = h;
#pragma unroll
    for (int off = 1; off < 64; off <<= 1) {
      const int y = __shfl_up(x, off, 64);
      if (t >= off) x += y;
    }
    gbase[t] = (x - h) + atomicAdd(&cursor[t], lhist[t]);
  }
  __syncthreads();
  idx[gbase[lab0] + r0] = i0;
  idx[gbase[lab1] + r1] = i1;
}

// 512 blocks = 64 classes x 8 ROW-SEGMENTS. Each block reads whole 2KB rows
// exactly once (128 threads x float4 = full row; 2 row-slots; 2-deep pipeline).
// LDS-reduce slots, 8-way atomicAdd into sums.
__global__ __launch_bounds__(256) void k_sumsC(const float* __restrict__ S1,
                                               const int* __restrict__ idx,
                                               const int* __restrict__ hist,
                                               float* __restrict__ sums) {
  __shared__ int sh_start[NCLS + 1];
  __shared__ floatx4 red4[128];
  const int c = blockIdx.x >> 3;
  const int g = blockIdx.x & 7;
  const int t = threadIdx.x;
  if (t < 64) {
    const int h = hist[t];
    int x = h;
#pragma unroll
    for (int off = 1; off < 64; off <<= 1) {
      const int y = __shfl_up(x, off, 64);
      if (t >= off) x += y;
    }
    sh_start[t] = x - h;
    if (t == 63) sh_start[64] = x;
  }
  __syncthreads();
  const int s0 = sh_start[c];
  const int n  = sh_start[c + 1] - s0;
  const int seg8 = n >> 3;
  const int base = s0 + g * seg8;
  const int len  = (g == 7) ? (n - 7 * seg8) : seg8;

  const int col4 = (t & 127) * 4;   // float column offset, covers all 512
  const int slot = t >> 7;          // 0/1: interleaved rows
  const int* ip = idx + base;
  floatx4 acc = {0.f, 0.f, 0.f, 0.f};
  int j = slot;
  if (len >= 8) {
    int ra = ip[j], rb = ip[j + 2];
    for (; j + 6 < len; j += 4) {
      const int na = ip[j + 4];
      const int nb = ip[j + 6];
      const floatx4 va = *(const floatx4*)(S1 + (size_t)ra * DDIM + col4);
      const floatx4 vb = *(const floatx4*)(S1 + (size_t)rb * DDIM + col4);
      acc = acc + va + vb;
      ra = na; rb = nb;
    }
    acc = acc + *(const floatx4*)(S1 + (size_t)ra * DDIM + col4);
    if (j + 2 < len)
      acc = acc + *(const floatx4*)(S1 + (size_t)rb * DDIM + col4);
    j += 4;
  }
  for (; j < len; j += 2)
    acc = acc + *(const floatx4*)(S1 + (size_t)ip[j] * DDIM + col4);

  if (slot == 1) red4[t & 127] = acc;
  __syncthreads();
  if (slot == 0) {
    const floatx4 s = acc + red4[t];
    float* dst = &sums[(size_t)c * DDIM + col4];
    atomicAdd(dst + 0, s[0]);
    atomicAdd(dst + 1, s[1]);
    atomicAdd(dst + 2, s[2]);
    atomicAdd(dst + 3, s[3]);
  }
}

// Persistent barrier-free GEMM+CE. 512 blocks x 512 threads, 256 rows/block.
// Cent staged to LDS once (fused divide+bf16, XOR-swizzled 16B granules).
// K-loop: unroll 1 + branchless depth-1 prefetch (no spill); epilogue has no
// dynamically-indexed locals (no scratch).
__global__ __launch_bounds__(512, 4) void k_loss(const float* __restrict__ S1,
                                                 const float* __restrict__ S2,
                                                 const int* __restrict__ seg,
                                                 const float* __restrict__ sim,
                                                 const float* __restrict__ sums,
                                                 const int* __restrict__ hist,
                                                 float* __restrict__ out) {
  __shared__ short cent[NCLS * DDIM];  // 64 KB, [class][k] swizzled: g' = g ^ (class&7)
  __shared__ float red8[8];
  const int t = threadIdx.x;

  {  // stage centroids: fused sums/count * 1/TEMP -> bf16
    const int cls = t >> 3;
    const float inv = 10.0f / (float)hist[cls];
    const float* sp = sums + (size_t)cls * DDIM;
#pragma unroll
    for (int i = 0; i < 8; ++i) {
      const int g = (t & 7) + i * 8;              // 16B granule index 0..63
      const float4 x = *(const float4*)(sp + g * 8);
      const float4 y = *(const float4*)(sp + g * 8 + 4);
      shortx8 b;
      b[0] = (short)f2bf(x.x * inv); b[1] = (short)f2bf(x.y * inv);
      b[2] = (short)f2bf(x.z * inv); b[3] = (short)f2bf(x.w * inv);
      b[4] = (short)f2bf(y.x * inv); b[5] = (short)f2bf(y.y * inv);
      b[6] = (short)f2bf(y.z * inv); b[7] = (short)f2bf(y.w * inv);
      *(shortx8*)&cent[cls * DDIM + ((g ^ (cls & 7)) * 8)] = b;
    }
  }
  __syncthreads();

  const int w    = t >> 6;
  const int lane = t & 63;
  const int n    = lane & 15;
  const int quad = lane >> 4;
  const int vb   = blockIdx.x * 256;
  const bool isS2 = (vb >= NROWS);
  const float* S = isS2 ? S2 : S1;
  const int i0m = isS2 ? (vb - NROWS) : vb;

  float loss_acc = 0.f;
#pragma unroll 1
  for (int s = 0; s < 2; ++s) {
    const int row0 = i0m + s * 128 + w * 16;
    const float* Srow = S + (size_t)(row0 + n) * DDIM;  // lane's A-row
    floatx4 acc0 = {0,0,0,0}, acc1 = {0,0,0,0}, acc2 = {0,0,0,0}, acc3 = {0,0,0,0};
    float4 aLo = *(const float4*)(Srow + quad * 8);
    float4 aHi = *(const float4*)(Srow + quad * 8 + 4);
#pragma unroll 1
    for (int c = 0; c < 16; ++c) {
      const int cn = (c + 1) & 15;   // branchless wrap (c=15 reloads warm line)
      const float4 nLo = *(const float4*)(Srow + cn * 32 + quad * 8);
      const float4 nHi = *(const float4*)(Srow + cn * 32 + quad * 8 + 4);
      shortx8 af;
      af[0] = (short)f2bf(aLo.x); af[1] = (short)f2bf(aLo.y);
      af[2] = (short)f2bf(aLo.z); af[3] = (short)f2bf(aLo.w);
      af[4] = (short)f2bf(aHi.x); af[5] = (short)f2bf(aHi.y);
      af[6] = (short)f2bf(aHi.z); af[7] = (short)f2bf(aHi.w);
      const int gp = ((c * 4 + quad) ^ (n & 7)) * 8;
      const shortx8 b0 = *(const shortx8*)&cent[(0  + n) * DDIM + gp];
      acc0 = __builtin_amdgcn_mfma_f32_16x16x32_bf16(af, b0, acc0, 0, 0, 0);
      const shortx8 b1 = *(const shortx8*)&cent[(16 + n) * DDIM + gp];
      acc1 = __builtin_amdgcn_mfma_f32_16x16x32_bf16(af, b1, acc1, 0, 0, 0);
      const shortx8 b2 = *(const shortx8*)&cent[(32 + n) * DDIM + gp];
      acc2 = __builtin_amdgcn_mfma_f32_16x16x32_bf16(af, b2, acc2, 0, 0, 0);
      const shortx8 b3 = *(const shortx8*)&cent[(48 + n) * DDIM + gp];
      acc3 = __builtin_amdgcn_mfma_f32_16x16x32_bf16(af, b3, acc3, 0, 0, 0);
      aLo = nLo; aHi = nHi;
    }
    // in-register CE epilogue. Row R = quad*4 + r; lane holds classes {n,16+n,32+n,48+n}.
#pragma unroll
    for (int r = 0; r < 4; ++r) {
      float mx = fmaxf(fmaxf(acc0[r], acc1[r]), fmaxf(acc2[r], acc3[r]));
      mx = fmaxf(mx, __shfl_xor(mx, 1, 16));
      mx = fmaxf(mx, __shfl_xor(mx, 2, 16));
      mx = fmaxf(mx, __shfl_xor(mx, 4, 16));
      mx = fmaxf(mx, __shfl_xor(mx, 8, 16));
      float se = __expf(acc0[r] - mx) + __expf(acc1[r] - mx) +
                 __expf(acc2[r] - mx) + __expf(acc3[r] - mx);
      se += __shfl_xor(se, 1, 16);
      se += __shfl_xor(se, 2, 16);
      se += __shfl_xor(se, 4, 16);
      se += __shfl_xor(se, 8, 16);
      const int lab = seg[row0 + quad * 4 + r];   // group-uniform
      const int ctl = lab >> 4, nl = lab & 15;
      float v = (ctl == 0) ? acc0[r] : (ctl == 1) ? acc1[r]
              : (ctl == 2) ? acc2[r] : acc3[r];
      const float lv = __shfl(v, nl, 16);         // class-lab logit
      const float ce = mx + __logf(se) - lv;
      if (n == r) {                               // lane r of each 16-group owns row quad*4+r
        const int R = row0 + quad * 4 + r;
        const float4* sp4 = (const float4*)&sim[(size_t)R * 16];
        const float4 w0 = sp4[0], w1 = sp4[1], w2 = sp4[2], w3 = sp4[3];
        const float wgt = (w0.x + w0.y + w0.z + w0.w + w1.x + w1.y + w1.z + w1.w +
                           w2.x + w2.y + w2.z + w2.w + w3.x + w3.y + w3.z + w3.w) * (1.0f / 16.0f);
        loss_acc += ce * wgt;
      }
    }
  }

  float v = loss_acc * SCALE;
#pragma unroll
  for (int off = 1; off < 64; off <<= 1) v += __shfl_xor(v, off, 64);
  if (lane == 0) red8[w] = v;
  __syncthreads();
  if (t == 0) {
    float sacc = red8[0] + red8[1] + red8[2] + red8[3] +
                 red8[4] + red8[5] + red8[6] + red8[7];
    atomicAdd(out, sacc);
  }
}

extern "C" void kernel_launch(void* const* d_in, const int* in_sizes, int n_in,
                              void* d_out, int out_size, void* d_ws, size_t ws_size,
                              hipStream_t stream) {
  const float* S1  = (const float*)d_in[0];
  const float* S2  = (const float*)d_in[1];
  const int*   seg = (const int*)d_in[2];
  const float* sim = (const float*)d_in[3];
  char* ws = (char*)d_ws;
  float* sums   = (float*)(ws + OFF_SUMS);
  int*   hist   = (int*)(ws + OFF_HIST);
  int*   cursor = (int*)(ws + OFF_CURSOR);
  int*   idx    = (int*)(ws + OFF_IDX);
  float* out = (float*)d_out;

  hipMemsetAsync(ws + OFF_HIST, 0, 512, stream);   // hist + cursor
  hipMemsetAsync(d_out, 0, sizeof(float), stream);

  k_hist<<<64, 256, 0, stream>>>(seg, hist);
  k_scatter2<<<32, 1024, 0, stream>>>(seg, hist, cursor, idx, sums);
  k_sumsC<<<512, 256, 0, stream>>>(S1, idx, hist, sums);
  k_loss<<<512, 512, 0, stream>>>(S1, S2, seg, sim, sums, hist, out);
}

// Round 7
// 308.342 us; speedup vs baseline: 1.3740x; 1.0031x over previous
//
#include <hip/hip_runtime.h>
#include <hip/hip_bf16.h>

#define NROWS 65536
#define DDIM  512
#define NCLS  64

typedef __attribute__((ext_vector_type(4))) float  floatx4;
typedef __attribute__((ext_vector_type(8))) short  shortx8;

static constexpr float SCALE = 0.25f / (float)NROWS;  // (1-GLW)/2 = GLW/2 = 0.25, / N

// ws byte offsets
static constexpr size_t OFF_SUMS   = 0;        // f32 [64][512] = 131072 B (zeroed by k_scatter2)
static constexpr size_t OFF_HIST   = 131072;   // int [64]
static constexpr size_t OFF_CURSOR = 131328;   // int [64]
static constexpr size_t OFF_IDX    = 131584;   // int [65536] = 262144 B

// packed f32x2 -> bf16x2 (v_cvt_pk_bf16_f32 on gfx950, RNE)
__device__ __forceinline__ shortx8 cvt8(const float4 lo, const float4 hi) {
  union { shortx8 v; __hip_bfloat162 p[4]; } u;
  u.p[0] = __float22bfloat162_rn(make_float2(lo.x, lo.y));
  u.p[1] = __float22bfloat162_rn(make_float2(lo.z, lo.w));
  u.p[2] = __float22bfloat162_rn(make_float2(hi.x, hi.y));
  u.p[3] = __float22bfloat162_rn(make_float2(hi.z, hi.w));
  return u.v;
}

// 64 blocks x 256 threads x 4 rows (int4)
__global__ __launch_bounds__(256) void k_hist(const int* __restrict__ seg,
                                              int* __restrict__ hist) {
  __shared__ int h[NCLS];
  const int t = threadIdx.x;
  if (t < NCLS) h[t] = 0;
  __syncthreads();
  const int4 v = ((const int4*)seg)[blockIdx.x * 256 + t];
  atomicAdd(&h[v.x], 1); atomicAdd(&h[v.y], 1);
  atomicAdd(&h[v.z], 1); atomicAdd(&h[v.w], 1);
  __syncthreads();
  if (t < NCLS) atomicAdd(&hist[t], h[t]);
}

// 32 blocks x 1024 threads x 2 rows. Rank via LDS atomic, base via one global
// atomic per class per block; global starts from hist via wave shfl-scan.
// Also zeroes sums[32768] (one float per thread) for k_sumsC's atomics.
__global__ __launch_bounds__(1024) void k_scatter2(const int* __restrict__ seg,
                                                   const int* __restrict__ hist,
                                                   int* __restrict__ cursor,
                                                   int* __restrict__ idx,
                                                   float* __restrict__ sums) {
  __shared__ int lhist[NCLS];
  __shared__ int gbase[NCLS];
  const int t = threadIdx.x;
  sums[blockIdx.x * 1024 + t] = 0.f;   // 32*1024 == 64*512 exactly
  if (t < NCLS) lhist[t] = 0;
  __syncthreads();
  const int i0 = blockIdx.x * 2048 + t;
  const int lab0 = seg[i0];
  const int r0 = atomicAdd(&lhist[lab0], 1);
  const int i1 = i0 + 1024;
  const int lab1 = seg[i1];
  const int r1 = atomicAdd(&lhist[lab1], 1);
  __syncthreads();
  if (t < NCLS) {
    const int h = hist[t];
    int x = h;
#pragma unroll
    for (int off = 1; off < 64; off <<= 1) {
      const int y = __shfl_up(x, off, 64);
      if (t >= off) x += y;
    }
    gbase[t] = (x - h) + atomicAdd(&cursor[t], lhist[t]);
  }
  __syncthreads();
  idx[gbase[lab0] + r0] = i0;
  idx[gbase[lab1] + r1] = i1;
}

// 512 blocks = 64 classes x 8 ROW-SEGMENTS. Each block reads whole 2KB rows
// exactly once (128 threads x float4 = full row; 2 row-slots; 2-deep pipeline).
// LDS-reduce slots, 8-way atomicAdd into sums.
__global__ __launch_bounds__(256) void k_sumsC(const float* __restrict__ S1,
                                               const int* __restrict__ idx,
                                               const int* __restrict__ hist,
                                               float* __restrict__ sums) {
  __shared__ int sh_start[NCLS + 1];
  __shared__ floatx4 red4[128];
  const int c = blockIdx.x >> 3;
  const int g = blockIdx.x & 7;
  const int t = threadIdx.x;
  if (t < 64) {
    const int h = hist[t];
    int x = h;
#pragma unroll
    for (int off = 1; off < 64; off <<= 1) {
      const int y = __shfl_up(x, off, 64);
      if (t >= off) x += y;
    }
    sh_start[t] = x - h;
    if (t == 63) sh_start[64] = x;
  }
  __syncthreads();
  const int s0 = sh_start[c];
  const int n  = sh_start[c + 1] - s0;
  const int seg8 = n >> 3;
  const int base = s0 + g * seg8;
  const int len  = (g == 7) ? (n - 7 * seg8) : seg8;

  const int col4 = (t & 127) * 4;   // float column offset, covers all 512
  const int slot = t >> 7;          // 0/1: interleaved rows
  const int* ip = idx + base;
  floatx4 acc = {0.f, 0.f, 0.f, 0.f};
  int j = slot;
  if (len >= 8) {
    int ra = ip[j], rb = ip[j + 2];
    for (; j + 6 < len; j += 4) {
      const int na = ip[j + 4];
      const int nb = ip[j + 6];
      const floatx4 va = *(const floatx4*)(S1 + (size_t)ra * DDIM + col4);
      const floatx4 vb = *(const floatx4*)(S1 + (size_t)rb * DDIM + col4);
      acc = acc + va + vb;
      ra = na; rb = nb;
    }
    acc = acc + *(const floatx4*)(S1 + (size_t)ra * DDIM + col4);
    if (j + 2 < len)
      acc = acc + *(const floatx4*)(S1 + (size_t)rb * DDIM + col4);
    j += 4;
  }
  for (; j < len; j += 2)
    acc = acc + *(const floatx4*)(S1 + (size_t)ip[j] * DDIM + col4);

  if (slot == 1) red4[t & 127] = acc;
  __syncthreads();
  if (slot == 0) {
    const floatx4 s = acc + red4[t];
    float* dst = &sums[(size_t)c * DDIM + col4];
    atomicAdd(dst + 0, s[0]);
    atomicAdd(dst + 1, s[1]);
    atomicAdd(dst + 2, s[2]);
    atomicAdd(dst + 3, s[3]);
  }
}

// Persistent barrier-free GEMM+CE. 512 blocks x 512 threads, 256 rows/block.
// Cent staged to LDS once (fused divide + packed bf16 cvt, XOR-swizzled 16B
// granules). K-loop: unroll 1 + branchless depth-1 prefetch (no spill);
// A-frag f32->bf16 via v_cvt_pk_bf16_f32 (8 VALU ops vs 64 for manual pack).
__global__ __launch_bounds__(512, 4) void k_loss(const float* __restrict__ S1,
                                                 const float* __restrict__ S2,
                                                 const int* __restrict__ seg,
                                                 const float* __restrict__ sim,
                                                 const float* __restrict__ sums,
                                                 const int* __restrict__ hist,
                                                 float* __restrict__ out) {
  __shared__ short cent[NCLS * DDIM];  // 64 KB, [class][k] swizzled: g' = g ^ (class&7)
  __shared__ float red8[8];
  const int t = threadIdx.x;

  {  // stage centroids: fused sums/count * 1/TEMP -> bf16
    const int cls = t >> 3;
    const float inv = 10.0f / (float)hist[cls];
    const float* sp = sums + (size_t)cls * DDIM;
#pragma unroll
    for (int i = 0; i < 8; ++i) {
      const int g = (t & 7) + i * 8;              // 16B granule index 0..63
      float4 x = *(const float4*)(sp + g * 8);
      float4 y = *(const float4*)(sp + g * 8 + 4);
      x.x *= inv; x.y *= inv; x.z *= inv; x.w *= inv;
      y.x *= inv; y.y *= inv; y.z *= inv; y.w *= inv;
      *(shortx8*)&cent[cls * DDIM + ((g ^ (cls & 7)) * 8)] = cvt8(x, y);
    }
  }
  __syncthreads();

  const int w    = t >> 6;
  const int lane = t & 63;
  const int n    = lane & 15;
  const int quad = lane >> 4;
  const int vb   = blockIdx.x * 256;
  const bool isS2 = (vb >= NROWS);
  const float* S = isS2 ? S2 : S1;
  const int i0m = isS2 ? (vb - NROWS) : vb;

  float loss_acc = 0.f;
#pragma unroll 1
  for (int s = 0; s < 2; ++s) {
    const int row0 = i0m + s * 128 + w * 16;
    const float* Srow = S + (size_t)(row0 + n) * DDIM;  // lane's A-row
    floatx4 acc0 = {0,0,0,0}, acc1 = {0,0,0,0}, acc2 = {0,0,0,0}, acc3 = {0,0,0,0};
    float4 aLo = *(const float4*)(Srow + quad * 8);
    float4 aHi = *(const float4*)(Srow + quad * 8 + 4);
#pragma unroll 1
    for (int c = 0; c < 16; ++c) {
      const int cn = (c + 1) & 15;   // branchless wrap (c=15 reloads warm line)
      const float4 nLo = *(const float4*)(Srow + cn * 32 + quad * 8);
      const float4 nHi = *(const float4*)(Srow + cn * 32 + quad * 8 + 4);
      const shortx8 af = cvt8(aLo, aHi);
      const int gp = ((c * 4 + quad) ^ (n & 7)) * 8;
      const shortx8 b0 = *(const shortx8*)&cent[(0  + n) * DDIM + gp];
      acc0 = __builtin_amdgcn_mfma_f32_16x16x32_bf16(af, b0, acc0, 0, 0, 0);
      const shortx8 b1 = *(const shortx8*)&cent[(16 + n) * DDIM + gp];
      acc1 = __builtin_amdgcn_mfma_f32_16x16x32_bf16(af, b1, acc1, 0, 0, 0);
      const shortx8 b2 = *(const shortx8*)&cent[(32 + n) * DDIM + gp];
      acc2 = __builtin_amdgcn_mfma_f32_16x16x32_bf16(af, b2, acc2, 0, 0, 0);
      const shortx8 b3 = *(const shortx8*)&cent[(48 + n) * DDIM + gp];
      acc3 = __builtin_amdgcn_mfma_f32_16x16x32_bf16(af, b3, acc3, 0, 0, 0);
      aLo = nLo; aHi = nHi;
    }
    // in-register CE epilogue. Row R = quad*4 + r; lane holds classes {n,16+n,32+n,48+n}.
#pragma unroll
    for (int r = 0; r < 4; ++r) {
      float mx = fmaxf(fmaxf(acc0[r], acc1[r]), fmaxf(acc2[r], acc3[r]));
      mx = fmaxf(mx, __shfl_xor(mx, 1, 16));
      mx = fmaxf(mx, __shfl_xor(mx, 2, 16));
      mx = fmaxf(mx, __shfl_xor(mx, 4, 16));
      mx = fmaxf(mx, __shfl_xor(mx, 8, 16));
      float se = __expf(acc0[r] - mx) + __expf(acc1[r] - mx) +
                 __expf(acc2[r] - mx) + __expf(acc3[r] - mx);
      se += __shfl_xor(se, 1, 16);
      se += __shfl_xor(se, 2, 16);
      se += __shfl_xor(se, 4, 16);
      se += __shfl_xor(se, 8, 16);
      const int lab = seg[row0 + quad * 4 + r];   // group-uniform
      const int ctl = lab >> 4, nl = lab & 15;
      float v = (ctl == 0) ? acc0[r] : (ctl == 1) ? acc1[r]
              : (ctl == 2) ? acc2[r] : acc3[r];
      const float lv = __shfl(v, nl, 16);         // class-lab logit
      const float ce = mx + __logf(se) - lv;
      if (n == r) {                               // lane r of each 16-group owns row quad*4+r
        const int R = row0 + quad * 4 + r;
        const float4* sp4 = (const float4*)&sim[(size_t)R * 16];
        const float4 w0 = sp4[0], w1 = sp4[1], w2 = sp4[2], w3 = sp4[3];
        const float wgt = (w0.x + w0.y + w0.z + w0.w + w1.x + w1.y + w1.z + w1.w +
                           w2.x + w2.y + w2.z + w2.w + w3.x + w3.y + w3.z + w3.w) * (1.0f / 16.0f);
        loss_acc += ce * wgt;
      }
    }
  }

  float v = loss_acc * SCALE;
#pragma unroll
  for (int off = 1; off < 64; off <<= 1) v += __shfl_xor(v, off, 64);
  if (lane == 0) red8[w] = v;
  __syncthreads();
  if (t == 0) {
    float sacc = red8[0] + red8[1] + red8[2] + red8[3] +
                 red8[4] + red8[5] + red8[6] + red8[7];
    atomicAdd(out, sacc);
  }
}

extern "C" void kernel_launch(void* const* d_in, const int* in_sizes, int n_in,
                              void* d_out, int out_size, void* d_ws, size_t ws_size,
                              hipStream_t stream) {
  const float* S1  = (const float*)d_in[0];
  const float* S2  = (const float*)d_in[1];
  const int*   seg = (const int*)d_in[2];
  const float* sim = (const float*)d_in[3];
  char* ws = (char*)d_ws;
  float* sums   = (float*)(ws + OFF_SUMS);
  int*   hist   = (int*)(ws + OFF_HIST);
  int*   cursor = (int*)(ws + OFF_CURSOR);
  int*   idx    = (int*)(ws + OFF_IDX);
  float* out = (float*)d_out;

  hipMemsetAsync(ws + OFF_HIST, 0, 512, stream);   // hist + cursor
  hipMemsetAsync(d_out, 0, sizeof(float), stream);

  k_hist<<<64, 256, 0, stream>>>(seg, hist);
  k_scatter2<<<32, 1024, 0, stream>>>(seg, hist, cursor, idx, sums);
  k_sumsC<<<512, 256, 0, stream>>>(S1, idx, hist, sums);
  k_loss<<<512, 512, 0, stream>>>(S1, S2, seg, sim, sums, hist, out);
}